// Round 10
// baseline (2385.654 us; speedup 1.0000x reference)
//
#include <hip/hip_runtime.h>
#include <stdint.h>

#define N_PTS 200000
#define HW3 35344            // 188*188
#define HW4 8836             // 94*94
#define OUT4_OFF 9048064     // 2*128*HW3
#define OUT_ELEMS 11310080   // OUT4_OFF + 2*128*HW4
// d_out scratch layout (ushort indices): stats [0,2M), vf16 [2M,6.48M)
#define S_FLOATS 1000000     // 100000 voxels * 10 fp32
#define F_UINTS  2240000     // 70000 voxels * 32 uint (64ch enc16 pairs)
#define G_USHORTS 3840000    // 30000 voxels * 128 enc16 (in d_ws)
#define G4_OFF 2560000       // vf4enc offset inside G
#define NB3 625              // 20000/32 scatter blocks, scale 3
#define NB4 313              // ceil(10000/32), scale 4
typedef unsigned short ushort_t;
typedef unsigned long long u64;

// ---- bf16 <-> fp32 ----
__device__ __forceinline__ float bfbits2f(unsigned hbits16) {
  return __uint_as_float(hbits16 << 16);
}
// RNE float->bf16 with NaN->0 and inf-saturation (output can never be NaN/inf)
__device__ __forceinline__ ushort_t f2bf(float f) {
  if (!(f == f)) return (ushort_t)0;                      // NaN -> +0
  unsigned u = __float_as_uint(f);
  if ((u & 0x7F800000u) == 0x7F800000u)                   // +-inf -> +-max finite
    return (ushort_t)(((u >> 16) & 0x8000u) | 0x7F7Fu);
  unsigned r = u + 0x7FFFu + ((u >> 16) & 1u);
  ushort_t h = (ushort_t)(r >> 16);
  if ((h & 0x7FFFu) == 0x7F80u) h = (ushort_t)((h & 0x8000u) | 0x7F7Fu); // rounded to inf
  return h;
}
// order-preserving 16-bit encode of bf16 bits
__device__ __forceinline__ unsigned enc16(unsigned h) {
  return (h & 0x8000u) ? (h ^ 0xFFFFu) : (h | 0x8000u);
}
__device__ __forceinline__ unsigned dec16(unsigned e) {
  return (e & 0x8000u) ? (e & 0x7FFFu) : (e ^ 0xFFFFu);
}
// enc16(0xFF7F = saturated FINFO_MIN) == 0x0080 (init value for max-buffers)

// 4x16-bit lane-wise scatter-max via 64-bit CAS (values monotone; masked compare
// works because same bit positions compare identically)
__device__ __forceinline__ void casMax64(u64* w, u64 enc) {
  u64 old = *w;
  while (true) {
    u64 nw = 0;
    #pragma unroll
    for (int i = 0; i < 4; i++) {
      u64 m = 0xFFFFull << (i * 16);
      u64 av = old & m, bv = enc & m;
      nw |= (av > bv) ? av : bv;
    }
    if (nw == old) break;
    u64 prev = atomicCAS(w, old, nw);
    if (prev == old) break;
    old = prev;
  }
}

struct ScaleArgs {
  const ushort_t* vlc[5];
  const int*      pv[5];
  float*          stats[5];   // in d_out scratch; per voxel stride 10
  unsigned*       vf16[3];    // in d_out scratch; [V][32] uints (2 enc16 ch/word)
};

// ---------------- K0: init scratch regions ----------------
__global__ void k_init(unsigned* __restrict__ outw, unsigned* __restrict__ g) {
  int i = blockIdx.x * blockDim.x + threadIdx.x;
  if (i < S_FLOATS) { outw[i] = 0u; return; }                      // stats = 0.0f
  if (i < S_FLOATS + F_UINTS) { outw[i] = 0x00800080u; return; }   // vf16 init
  i -= S_FLOATS + F_UINTS;
  if (i < G_USHORTS / 2) g[i] = 0x00800080u;                       // vf3/vf4 init
}

// ---------------- K1: per-scale segment sums ----------------
__global__ void __launch_bounds__(256) k_segsum(const ushort4* __restrict__ points, ScaleArgs a) {
  int p = blockIdx.x * blockDim.x + threadIdx.x;
  if (p >= N_PTS) return;
  ushort4 pu = points[p];
  float px = bfbits2f(pu.x), py = bfbits2f(pu.y), pz = bfbits2f(pu.z), pw = bfbits2f(pu.w);
  #pragma unroll
  for (int s = 0; s < 5; s++) {
    int v = a.pv[s][p];
    float l0 = bfbits2f(a.vlc[s][3 * p + 0]);
    float l1 = bfbits2f(a.vlc[s][3 * p + 1]);
    float* st = a.stats[s] + (size_t)v * 10;
    atomicAdd(st + 0, px);
    atomicAdd(st + 1, py);
    atomicAdd(st + 2, pz);
    atomicAdd(st + 3, pw);
    atomicAdd(st + 4, l0);
    atomicAdd(st + 5, l1);
    atomicAdd(st + 9, 1.0f);
  }
}

// ---------------- K2: sums -> a2 (per-voxel means) ----------------
__global__ void k_voxstats(ScaleArgs a) {
  int i = blockIdx.x * blockDim.x + threadIdx.x;
  int s, v;
  if      (i <  40000) { s = 0; v = i; }
  else if (i <  60000) { s = 1; v = i - 40000; }
  else if (i <  70000) { s = 2; v = i - 60000; }
  else if (i <  90000) { s = 3; v = i - 70000; }
  else if (i < 100000) { s = 4; v = i - 90000; }
  else return;
  float* st = a.stats[s] + (size_t)v * 10;
  float cnt = st[9];
  float c = fmaxf(cnt, 1.0f);
  float s0 = st[0], s1 = st[1], s2 = st[2], s3 = st[3], s4 = st[4], s5 = st[5];
  float pm0 = s0 / c, pm1 = s1 / c, pm2 = s2 / c, pm3 = s3 / c;
  float mp0 = (s0 - cnt * pm0) / c;
  float mp1 = (s1 - cnt * pm1) / c;
  float mp2 = (s2 - cnt * pm2) / c;
  float mv0 = s4 / c, mv1 = s5 / c;
  st[0] = pm0; st[1] = pm1; st[2] = pm2; st[3] = pm3;
  st[4] = mp0; st[5] = mp1; st[6] = mp2; st[7] = mv0; st[8] = mv1;
}

// ---------------- K3: scales 0-2, final -> 64-bit CAS-max into vf16 ----------------
__global__ void __launch_bounds__(256) k_scale012(
    const ushort4* __restrict__ points, ScaleArgs a,
    const ushort_t* __restrict__ Wp,   // [9][64] bf16
    const ushort_t* __restrict__ Wa) { // [18][64] bf16
  __shared__ float WpS[9 * 64];
  __shared__ float WaS[18 * 64];
  int tid = threadIdx.x;
  for (int i = tid; i < 9 * 64; i += 256)  WpS[i] = bfbits2f(Wp[i]);
  for (int i = tid; i < 18 * 64; i += 256) WaS[i] = bfbits2f(Wa[i]);
  __syncthreads();

  int p = blockIdx.x * blockDim.x + tid;
  if (p >= N_PTS) return;
  ushort4 pu = points[p];
  float px = bfbits2f(pu.x), py = bfbits2f(pu.y), pz = bfbits2f(pu.z), pw = bfbits2f(pu.w);
  #pragma unroll 1
  for (int s = 0; s < 3; s++) {
    int v = a.pv[s][p];
    const float* st = a.stats[s] + (size_t)v * 10;
    float a2[9];
    #pragma unroll
    for (int k = 0; k < 9; k++) a2[k] = st[k];
    float plc0 = px - a2[0], plc1 = py - a2[1], plc2 = pz - a2[2];
    float vl0 = bfbits2f(a.vlc[s][3 * p + 0]);
    float vl1 = bfbits2f(a.vlc[s][3 * p + 1]);
    float pif[9] = {px, py, pz, pw, plc0, plc1, plc2, vl0, vl1};
    float att[18] = {plc0, plc1, plc2, pw, plc0, plc1, plc2, vl0, vl1,
                     a2[0], a2[1], a2[2], a2[3], a2[4], a2[5], a2[6], a2[7], a2[8]};
    unsigned* vfw = a.vf16[s] + (size_t)v * 32;
    #pragma unroll 1
    for (int cb = 0; cb < 64; cb += 16) {
      float accp[16], acca[16];
      #pragma unroll
      for (int l = 0; l < 16; l++) { accp[l] = 0.0f; acca[l] = 0.0f; }
      #pragma unroll
      for (int k = 0; k < 9; k++) {
        float x = pif[k];
        #pragma unroll
        for (int l = 0; l < 16; l++) accp[l] = fmaf(x, WpS[k * 64 + cb + l], accp[l]);
      }
      #pragma unroll
      for (int k = 0; k < 18; k++) {
        float x = att[k];
        #pragma unroll
        for (int l = 0; l < 16; l++) acca[l] = fmaf(x, WaS[k * 64 + cb + l], acca[l]);
      }
      #pragma unroll
      for (int l = 0; l < 16; l += 4) {
        u64 e = (u64)enc16(f2bf(acca[l] * accp[l]))
              | ((u64)enc16(f2bf(acca[l + 1] * accp[l + 1])) << 16)
              | ((u64)enc16(f2bf(acca[l + 2] * accp[l + 2])) << 32)
              | ((u64)enc16(f2bf(acca[l + 3] * accp[l + 3])) << 48);
        casMax64((u64*)(vfw + ((cb + l) >> 1)), e);
      }
    }
  }
}

// ---------------- K4: fused big GEMM, M=128 tile, B from L2 + scales 3/4 -> G ----------------
struct K4Args {
  const ushort4* points;
  const ushort_t* vlc[5];
  const int* pv[5];
  const float* stats[5];
  const unsigned* vf16[3];
  ushort_t* G;               // vf3enc at 0, vf4enc at G4_OFF; [v][c] layout
  const ushort_t* Wp;        // [9][64]
  const ushort_t* Wa;        // [18][64]
  const ushort_t* Wpo;       // [384][128]
  const ushort_t* Wao;       // [18][128]
};

__global__ void __launch_bounds__(256, 3) k_big(K4Args a) {
  __shared__ __align__(16) float A[128][68];   // A tile fp32; reused as WaoE in epilogue
  __shared__ __align__(16) float WpS[9][64];
  __shared__ __align__(16) float WaS[18][64];
  __shared__ __align__(16) float attS[128][20];
  __shared__ int pvAll[5][128];
  // LDS = 34816+2304+4608+10240+2560 = 54,528 B -> 3 blocks/CU fits (163,584 <= 163,840)

  int tid = threadIdx.x;
  int p0 = blockIdx.x * 128;
  int pIdx = min(p0 + tid, N_PTS - 1);   // pad rows clamp; outputs via max => idempotent

  for (int i = tid; i < 9 * 64; i += 256)   WpS[0][i]  = bfbits2f(a.Wp[i]);
  for (int i = tid; i < 18 * 64; i += 256)  WaS[0][i]  = bfbits2f(a.Wa[i]);
  float4 pt = make_float4(0.f, 0.f, 0.f, 0.f);
  if (tid < 128) {
    #pragma unroll
    for (int s = 0; s < 5; s++) pvAll[s][tid] = a.pv[s][pIdx];
    ushort4 pu = a.points[pIdx];
    pt = make_float4(bfbits2f(pu.x), bfbits2f(pu.y), bfbits2f(pu.z), bfbits2f(pu.w));
  }
  __syncthreads();

  int pr = tid & 7;        // point row group: rows pr, pr+8, ..., pr+120
  int cg = tid >> 3;       // 0..31
  int cb4 = cg << 2;       // channel base (4 channels)

  float acc[16][4];
  #pragma unroll
  for (int j = 0; j < 16; j++)
    #pragma unroll
    for (int l = 0; l < 4; l++) acc[j][l] = 0.0f;

  const uint2* Bg = (const uint2*)a.Wpo;   // uint2 = 4 bf16 = channels [cb4..cb4+3] at word cg

  #pragma unroll 1
  for (int kc = 0; kc < 6; kc++) {
    int s = kc >> 1;
    if ((kc & 1) == 0) {
      // ---- recompute final_s for 128 points ----
      if (tid < 128) {
        int v = pvAll[s][tid];
        const float* st = a.stats[s] + (size_t)v * 10;
        float a2k[9];
        #pragma unroll
        for (int k = 0; k < 9; k++) a2k[k] = st[k];
        float vl0 = bfbits2f(a.vlc[s][3 * pIdx + 0]);
        float vl1 = bfbits2f(a.vlc[s][3 * pIdx + 1]);
        float* row = attS[tid];
        row[0] = pt.x; row[1] = pt.y; row[2] = pt.z; row[3] = pt.w;
        row[4] = pt.x - a2k[0]; row[5] = pt.y - a2k[1]; row[6] = pt.z - a2k[2];
        row[7] = vl0; row[8] = vl1;
        #pragma unroll
        for (int k = 0; k < 9; k++) row[9 + k] = a2k[k];
      }
      __syncthreads();
      #pragma unroll 1
      for (int pp = 0; pp < 2; pp++) {
        int p = pp * 64 + (tid >> 2), ch0 = (tid & 3) << 4;
        float pv_[18];
        #pragma unroll
        for (int k = 0; k < 18; k++) pv_[k] = attS[p][k];
        float accp[16], acca[16];
        #pragma unroll
        for (int l = 0; l < 16; l++) { accp[l] = 0.0f; acca[l] = 0.0f; }
        #pragma unroll
        for (int k = 0; k < 9; k++) {
          float x = pv_[k];
          #pragma unroll
          for (int l = 0; l < 16; l++) accp[l] = fmaf(x, WpS[k][ch0 + l], accp[l]);
        }
        #pragma unroll
        for (int k = 0; k < 18; k++) {
          int src = (k < 3) ? (4 + k) : (k == 3) ? 3 : k;
          float x = pv_[src];
          #pragma unroll
          for (int l = 0; l < 16; l++) acca[l] = fmaf(x, WaS[k][ch0 + l], acca[l]);
        }
        #pragma unroll
        for (int l4 = 0; l4 < 16; l4 += 4) {
          float4 f;
          f.x = accp[l4 + 0] * acca[l4 + 0];
          f.y = accp[l4 + 1] * acca[l4 + 1];
          f.z = accp[l4 + 2] * acca[l4 + 2];
          f.w = accp[l4 + 3] * acca[l4 + 3];
          *(float4*)&A[p][ch0 + l4] = f;
        }
      }
    } else {
      // ---- gather vf_s[pv] (decode ordering) ----
      const unsigned* vfw = a.vf16[s];
      for (int i = tid; i < 4096; i += 256) {
        int p = i >> 5; int wd = i & 31;
        int v = pvAll[s][p];
        unsigned q = vfw[(size_t)v * 32 + wd];
        A[p][2 * wd]     = bfbits2f(dec16(q & 0xFFFFu));
        A[p][2 * wd + 1] = bfbits2f(dec16(q >> 16));
      }
    }
    __syncthreads();
    // ---- GEMM: B direct from global (L2-resident) ----
    #pragma unroll 1
    for (int kk = 0; kk < 64; kk += 4) {
      uint2 bw[4];
      #pragma unroll
      for (int t = 0; t < 4; t++) bw[t] = Bg[(size_t)(kc * 64 + kk + t) * 32 + cg];
      float bf[4][4];
      #pragma unroll
      for (int t = 0; t < 4; t++) {
        bf[t][0] = __uint_as_float(bw[t].x << 16);
        bf[t][1] = __uint_as_float(bw[t].x & 0xFFFF0000u);
        bf[t][2] = __uint_as_float(bw[t].y << 16);
        bf[t][3] = __uint_as_float(bw[t].y & 0xFFFF0000u);
      }
      #pragma unroll
      for (int jh = 0; jh < 2; jh++) {
        float4 av[8];
        #pragma unroll
        for (int j8 = 0; j8 < 8; j8++) av[j8] = *(const float4*)&A[pr + ((jh * 8 + j8) << 3)][kk];
        #pragma unroll
        for (int t = 0; t < 4; t++) {
          #pragma unroll
          for (int j8 = 0; j8 < 8; j8++) {
            float x = (t == 0) ? av[j8].x : (t == 1) ? av[j8].y : (t == 2) ? av[j8].z : av[j8].w;
            int j = jh * 8 + j8;
            acc[j][0] = fmaf(x, bf[t][0], acc[j][0]);
            acc[j][1] = fmaf(x, bf[t][1], acc[j][1]);
            acc[j][2] = fmaf(x, bf[t][2], acc[j][2]);
            acc[j][3] = fmaf(x, bf[t][3], acc[j][3]);
          }
        }
      }
    }
    __syncthreads();
  }

  // stage Wao (fp32) into A's LDS space -- A tile is dead after the K loop
  float* WaoE = &A[0][0];
  for (int i = tid; i < 18 * 128; i += 256) WaoE[i] = bfbits2f(a.Wao[i]);

  // epilogue: scales 3 & 4 -> 64-bit CAS-max into G ([v][c] layout)
  #pragma unroll 1
  for (int si = 0; si < 2; si++) {
    if (tid < 128) {
      int v = pvAll[3 + si][tid];
      const float* st = a.stats[3 + si] + (size_t)v * 10;
      float a2k[9];
      #pragma unroll
      for (int k = 0; k < 9; k++) a2k[k] = st[k];
      float vl0 = bfbits2f(a.vlc[3 + si][3 * pIdx + 0]);
      float vl1 = bfbits2f(a.vlc[3 + si][3 * pIdx + 1]);
      float plc0 = pt.x - a2k[0], plc1 = pt.y - a2k[1], plc2 = pt.z - a2k[2];
      float* row = attS[tid];
      row[0] = plc0; row[1] = plc1; row[2] = plc2; row[3] = pt.w;
      row[4] = plc0; row[5] = plc1; row[6] = plc2; row[7] = vl0; row[8] = vl1;
      #pragma unroll
      for (int k = 0; k < 9; k++) row[9 + k] = a2k[k];
    }
    __syncthreads();   // covers WaoE staging (si=0) and attS rebuild (both)
    size_t gbase = si ? (size_t)G4_OFF : 0;
    float afc[16][4];
    #pragma unroll
    for (int j = 0; j < 16; j++)
      #pragma unroll
      for (int l = 0; l < 4; l++) afc[j][l] = 0.0f;
    #pragma unroll 1
    for (int k = 0; k < 18; k++) {
      float4 w = *(const float4*)&WaoE[k * 128 + cb4];
      #pragma unroll
      for (int j = 0; j < 16; j++) {
        float x = attS[pr + (j << 3)][k];
        afc[j][0] = fmaf(x, w.x, afc[j][0]);
        afc[j][1] = fmaf(x, w.y, afc[j][1]);
        afc[j][2] = fmaf(x, w.z, afc[j][2]);
        afc[j][3] = fmaf(x, w.w, afc[j][3]);
      }
    }
    #pragma unroll
    for (int j = 0; j < 16; j++) {
      int p = pr + (j << 3);
      int v = pvAll[3 + si][p];
      u64 e = (u64)enc16(f2bf(afc[j][0] * acc[j][0]))
            | ((u64)enc16(f2bf(afc[j][1] * acc[j][1])) << 16)
            | ((u64)enc16(f2bf(afc[j][2] * acc[j][2])) << 32)
            | ((u64)enc16(f2bf(afc[j][3] * acc[j][3])) << 48);
      casMax64((u64*)(a.G + gbase + (size_t)v * 128 + cb4), e);
    }
    __syncthreads();
  }
}

// ---------------- K5: clear all of d_out ----------------
__global__ void k_clear(unsigned* __restrict__ outw) {
  int i = blockIdx.x * blockDim.x + threadIdx.x;
  if (i < OUT_ELEMS / 2) outw[i] = 0u;
}

// ---------------- K6: scatter G -> dense output, LDS-transposed tiles ----------------
__global__ void __launch_bounds__(256) k_scatter_out(const ushort_t* __restrict__ G,
                                                     const int* __restrict__ vfs3,
                                                     const int* __restrict__ vfs4,
                                                     ushort_t* __restrict__ out16) {
  __shared__ ushort_t tile[32][130];   // pad 130 -> conflict-free column reads
  __shared__ int vbase[32];
  int blk = blockIdx.x;
  int s = (blk >= NB3) ? 1 : 0;
  int v0 = (s ? (blk - NB3) : blk) * 32;
  int V = s ? 10000 : 20000;
  int HW = s ? HW4 : HW3;
  int W = s ? 94 : 188;
  const int* vfs = s ? vfs4 : vfs3;
  size_t goff = s ? (size_t)G4_OFF : 0;
  size_t ooff = s ? (size_t)OUT4_OFF : 0;
  int nv = min(32, V - v0);
  int tid = threadIdx.x;
  const unsigned* gw = (const unsigned*)(G + goff);
  for (int i = tid; i < nv * 64; i += 256) {
    int vi = i >> 6, cw = i & 63;
    unsigned q = gw[(size_t)(v0 + vi) * 64 + cw];
    tile[vi][2 * cw]     = (ushort_t)(q & 0xFFFFu);
    tile[vi][2 * cw + 1] = (ushort_t)(q >> 16);
  }
  if (tid < nv) {
    int v = v0 + tid;
    int b = vfs[3 * v], y = vfs[3 * v + 1], x = vfs[3 * v + 2];
    vbase[tid] = (b * 128) * HW + y * W + x;
  }
  __syncthreads();
  for (int i = tid; i < 128 * 32; i += 256) {
    int c = i >> 5, vi = i & 31;
    if (vi < nv) {
      unsigned d = dec16(tile[vi][c]);
      if ((d & 0x7F80u) == 0x7F80u) d = (d & 0x8000u) | 0x7F7Fu;  // scrub
      out16[ooff + (size_t)vbase[vi] + (size_t)c * HW] = (ushort_t)d;
    }
  }
}

// ---------------- host ----------------
extern "C" void kernel_launch(void* const* d_in, const int* in_sizes, int n_in,
                              void* d_out, int out_size, void* d_ws, size_t ws_size,
                              hipStream_t stream) {
  static const int VOX[5] = {40000, 20000, 10000, 20000, 10000};

  const ushort_t* points = (const ushort_t*)d_in[0];
  const ushort_t* vlc[5]; const int* pv[5]; const int* vfs[5];
  const ushort_t *Wp, *Wa, *Wpo, *Wao;
  if (in_sizes[2] == N_PTS) {
    for (int s = 0; s < 5; s++) {
      vlc[s] = (const ushort_t*)d_in[1 + 3 * s];
      pv[s]  = (const int*)     d_in[2 + 3 * s];
      vfs[s] = (const int*)     d_in[3 + 3 * s];
    }
    Wp  = (const ushort_t*)d_in[16];
    Wa  = (const ushort_t*)d_in[17];
    Wpo = (const ushort_t*)d_in[18];
    Wao = (const ushort_t*)d_in[19];
  } else {
    for (int s = 0; s < 5; s++) vlc[s] = (const ushort_t*)d_in[1 + s];
    Wp  = (const ushort_t*)d_in[6];
    Wa  = (const ushort_t*)d_in[7];
    Wpo = (const ushort_t*)d_in[8];
    Wao = (const ushort_t*)d_in[9];
    for (int s = 0; s < 5; s++) pv[s]  = (const int*)d_in[10 + s];
    for (int s = 0; s < 5; s++) vfs[s] = (const int*)d_in[15 + s];
  }

  // scratch: stats + vf16 inside d_out; G (vf3/vf4 enc) in d_ws (7.68 MB)
  float* statsBase = (float*)d_out;
  unsigned* outw = (unsigned*)d_out;
  unsigned* fBase = outw + S_FLOATS;
  ushort_t* G = (ushort_t*)d_ws;
  ushort_t* out16 = (ushort_t*)d_out;

  float* stats[5];
  size_t offS = 0;
  for (int s = 0; s < 5; s++) { stats[s] = statsBase + offS; offS += (size_t)VOX[s] * 10; }
  unsigned* vf16[3];
  size_t offF = 0;
  for (int s = 0; s < 3; s++) { vf16[s] = fBase + offF; offF += (size_t)VOX[s] * 32; }

  ScaleArgs sa;
  for (int s = 0; s < 5; s++) { sa.vlc[s] = vlc[s]; sa.pv[s] = pv[s]; sa.stats[s] = stats[s]; }
  for (int s = 0; s < 3; s++) sa.vf16[s] = vf16[s];

  int totInit = S_FLOATS + F_UINTS + G_USHORTS / 2;
  k_init<<<(totInit + 255) / 256, 256, 0, stream>>>(outw, (unsigned*)d_ws);

  k_segsum<<<(N_PTS + 255) / 256, 256, 0, stream>>>((const ushort4*)points, sa);

  k_voxstats<<<(100000 + 255) / 256, 256, 0, stream>>>(sa);

  k_scale012<<<(N_PTS + 255) / 256, 256, 0, stream>>>((const ushort4*)points, sa, Wp, Wa);

  K4Args ka;
  ka.points = (const ushort4*)points;
  for (int s = 0; s < 5; s++) { ka.vlc[s] = vlc[s]; ka.pv[s] = pv[s]; ka.stats[s] = stats[s]; }
  for (int s = 0; s < 3; s++) ka.vf16[s] = vf16[s];
  ka.G = G;
  ka.Wp = Wp; ka.Wa = Wa; ka.Wpo = Wpo; ka.Wao = Wao;
  k_big<<<(N_PTS + 127) / 128, 256, 0, stream>>>(ka);

  k_clear<<<(OUT_ELEMS / 2 + 255) / 256, 256, 0, stream>>>(outw);

  k_scatter_out<<<NB3 + NB4, 256, 0, stream>>>(G, vfs[3], vfs[4], out16);
}

// Round 11
// 1662.051 us; speedup vs baseline: 1.4354x; 1.4354x over previous
//
#include <hip/hip_runtime.h>
#include <stdint.h>

#define N_PTS 200000
#define HW3 35344            // 188*188
#define HW4 8836             // 94*94
#define OUT4_OFF 9048064     // 2*128*HW3
#define OUT_ELEMS 11310080   // OUT4_OFF + 2*128*HW4
// d_out scratch layout (ushort indices): stats [0,2M), vf16 [2M,6.48M)
#define S_FLOATS 1000000     // 100000 voxels * 10 fp32
#define F_UINTS  2240000     // 70000 voxels * 32 uint (64ch enc16 pairs)
#define G_USHORTS 3840000    // 30000 voxels * 128 enc16 (in d_ws)
#define G4_OFF 2560000       // vf4enc offset inside G
#define NB3 625              // 20000/32 scatter blocks, scale 3
#define NB4 313              // ceil(10000/32), scale 4
typedef unsigned short ushort_t;
typedef unsigned long long u64;

// ---- bf16 <-> fp32 ----
__device__ __forceinline__ float bfbits2f(unsigned hbits16) {
  return __uint_as_float(hbits16 << 16);
}
// RNE float->bf16 with NaN->0 and inf-saturation (output can never be NaN/inf)
__device__ __forceinline__ ushort_t f2bf(float f) {
  if (!(f == f)) return (ushort_t)0;                      // NaN -> +0
  unsigned u = __float_as_uint(f);
  if ((u & 0x7F800000u) == 0x7F800000u)                   // +-inf -> +-max finite
    return (ushort_t)(((u >> 16) & 0x8000u) | 0x7F7Fu);
  unsigned r = u + 0x7FFFu + ((u >> 16) & 1u);
  ushort_t h = (ushort_t)(r >> 16);
  if ((h & 0x7FFFu) == 0x7F80u) h = (ushort_t)((h & 0x8000u) | 0x7F7Fu); // rounded to inf
  return h;
}
// order-preserving 16-bit encode of bf16 bits
__device__ __forceinline__ unsigned enc16(unsigned h) {
  return (h & 0x8000u) ? (h ^ 0xFFFFu) : (h | 0x8000u);
}
__device__ __forceinline__ unsigned dec16(unsigned e) {
  return (e & 0x8000u) ? (e & 0x7FFFu) : (e ^ 0xFFFFu);
}
// enc16(0xFF7F = saturated FINFO_MIN) == 0x0080 (init value for max-buffers)

// 4x16-bit lane-wise scatter-max via 64-bit CAS (values monotone; masked compare
// works because same bit positions compare identically)
__device__ __forceinline__ void casMax64(u64* w, u64 enc) {
  u64 old = *w;
  while (true) {
    u64 nw = 0;
    #pragma unroll
    for (int i = 0; i < 4; i++) {
      u64 m = 0xFFFFull << (i * 16);
      u64 av = old & m, bv = enc & m;
      nw |= (av > bv) ? av : bv;
    }
    if (nw == old) break;
    u64 prev = atomicCAS(w, old, nw);
    if (prev == old) break;
    old = prev;
  }
}

struct ScaleArgs {
  const ushort_t* vlc[5];
  const int*      pv[5];
  float*          stats[5];   // in d_out scratch; per voxel stride 10
  unsigned*       vf16[3];    // in d_out scratch; [V][32] uints (2 enc16 ch/word)
};

// ---------------- K0: init scratch regions ----------------
__global__ void k_init(unsigned* __restrict__ outw, unsigned* __restrict__ g) {
  int i = blockIdx.x * blockDim.x + threadIdx.x;
  if (i < S_FLOATS) { outw[i] = 0u; return; }                      // stats = 0.0f
  if (i < S_FLOATS + F_UINTS) { outw[i] = 0x00800080u; return; }   // vf16 init
  i -= S_FLOATS + F_UINTS;
  if (i < G_USHORTS / 2) g[i] = 0x00800080u;                       // vf3/vf4 init
}

// ---------------- K1: per-scale segment sums ----------------
__global__ void __launch_bounds__(256) k_segsum(const ushort4* __restrict__ points, ScaleArgs a) {
  int p = blockIdx.x * blockDim.x + threadIdx.x;
  if (p >= N_PTS) return;
  ushort4 pu = points[p];
  float px = bfbits2f(pu.x), py = bfbits2f(pu.y), pz = bfbits2f(pu.z), pw = bfbits2f(pu.w);
  #pragma unroll
  for (int s = 0; s < 5; s++) {
    int v = a.pv[s][p];
    float l0 = bfbits2f(a.vlc[s][3 * p + 0]);
    float l1 = bfbits2f(a.vlc[s][3 * p + 1]);
    float* st = a.stats[s] + (size_t)v * 10;
    atomicAdd(st + 0, px);
    atomicAdd(st + 1, py);
    atomicAdd(st + 2, pz);
    atomicAdd(st + 3, pw);
    atomicAdd(st + 4, l0);
    atomicAdd(st + 5, l1);
    atomicAdd(st + 9, 1.0f);
  }
}

// ---------------- K2: sums -> a2 (per-voxel means) ----------------
__global__ void k_voxstats(ScaleArgs a) {
  int i = blockIdx.x * blockDim.x + threadIdx.x;
  int s, v;
  if      (i <  40000) { s = 0; v = i; }
  else if (i <  60000) { s = 1; v = i - 40000; }
  else if (i <  70000) { s = 2; v = i - 60000; }
  else if (i <  90000) { s = 3; v = i - 70000; }
  else if (i < 100000) { s = 4; v = i - 90000; }
  else return;
  float* st = a.stats[s] + (size_t)v * 10;
  float cnt = st[9];
  float c = fmaxf(cnt, 1.0f);
  float s0 = st[0], s1 = st[1], s2 = st[2], s3 = st[3], s4 = st[4], s5 = st[5];
  float pm0 = s0 / c, pm1 = s1 / c, pm2 = s2 / c, pm3 = s3 / c;
  float mp0 = (s0 - cnt * pm0) / c;
  float mp1 = (s1 - cnt * pm1) / c;
  float mp2 = (s2 - cnt * pm2) / c;
  float mv0 = s4 / c, mv1 = s5 / c;
  st[0] = pm0; st[1] = pm1; st[2] = pm2; st[3] = pm3;
  st[4] = mp0; st[5] = mp1; st[6] = mp2; st[7] = mv0; st[8] = mv1;
}

// ---------------- K3: scales 0-2, final -> 64-bit CAS-max into vf16 ----------------
__global__ void __launch_bounds__(256) k_scale012(
    const ushort4* __restrict__ points, ScaleArgs a,
    const ushort_t* __restrict__ Wp,   // [9][64] bf16
    const ushort_t* __restrict__ Wa) { // [18][64] bf16
  __shared__ float WpS[9 * 64];
  __shared__ float WaS[18 * 64];
  int tid = threadIdx.x;
  for (int i = tid; i < 9 * 64; i += 256)  WpS[i] = bfbits2f(Wp[i]);
  for (int i = tid; i < 18 * 64; i += 256) WaS[i] = bfbits2f(Wa[i]);
  __syncthreads();

  int p = blockIdx.x * blockDim.x + tid;
  if (p >= N_PTS) return;
  ushort4 pu = points[p];
  float px = bfbits2f(pu.x), py = bfbits2f(pu.y), pz = bfbits2f(pu.z), pw = bfbits2f(pu.w);
  #pragma unroll 1
  for (int s = 0; s < 3; s++) {
    int v = a.pv[s][p];
    const float* st = a.stats[s] + (size_t)v * 10;
    float a2[9];
    #pragma unroll
    for (int k = 0; k < 9; k++) a2[k] = st[k];
    float plc0 = px - a2[0], plc1 = py - a2[1], plc2 = pz - a2[2];
    float vl0 = bfbits2f(a.vlc[s][3 * p + 0]);
    float vl1 = bfbits2f(a.vlc[s][3 * p + 1]);
    float pif[9] = {px, py, pz, pw, plc0, plc1, plc2, vl0, vl1};
    float att[18] = {plc0, plc1, plc2, pw, plc0, plc1, plc2, vl0, vl1,
                     a2[0], a2[1], a2[2], a2[3], a2[4], a2[5], a2[6], a2[7], a2[8]};
    unsigned* vfw = a.vf16[s] + (size_t)v * 32;
    #pragma unroll 1
    for (int cb = 0; cb < 64; cb += 16) {
      float accp[16], acca[16];
      #pragma unroll
      for (int l = 0; l < 16; l++) { accp[l] = 0.0f; acca[l] = 0.0f; }
      #pragma unroll
      for (int k = 0; k < 9; k++) {
        float x = pif[k];
        #pragma unroll
        for (int l = 0; l < 16; l++) accp[l] = fmaf(x, WpS[k * 64 + cb + l], accp[l]);
      }
      #pragma unroll
      for (int k = 0; k < 18; k++) {
        float x = att[k];
        #pragma unroll
        for (int l = 0; l < 16; l++) acca[l] = fmaf(x, WaS[k * 64 + cb + l], acca[l]);
      }
      #pragma unroll
      for (int l = 0; l < 16; l += 4) {
        u64 e = (u64)enc16(f2bf(acca[l] * accp[l]))
              | ((u64)enc16(f2bf(acca[l + 1] * accp[l + 1])) << 16)
              | ((u64)enc16(f2bf(acca[l + 2] * accp[l + 2])) << 32)
              | ((u64)enc16(f2bf(acca[l + 3] * accp[l + 3])) << 48);
        casMax64((u64*)(vfw + ((cb + l) >> 1)), e);
      }
    }
  }
}

// ---------------- K4: fused big GEMM (M=64, B direct from L2) + scales 3/4 -> G ----------------
struct K4Args {
  const ushort4* points;
  const ushort_t* vlc[5];
  const int* pv[5];
  const float* stats[5];
  const unsigned* vf16[3];
  ushort_t* G;               // vf3enc at 0, vf4enc at G4_OFF; [v][c] layout
  const ushort_t* Wp;        // [9][64]
  const ushort_t* Wa;        // [18][64]
  const ushort_t* Wpo;       // [384][128]
  const ushort_t* Wao;       // [18][128]
};

__global__ void __launch_bounds__(256, 3) k_big(K4Args a) {
  __shared__ __align__(16) float A[64][68];   // A tile fp32; reused as WaoE in epilogue
  __shared__ __align__(16) float WpS[9][64];
  __shared__ __align__(16) float WaS[18][64];
  __shared__ __align__(16) float attS[64][20];
  __shared__ int pvAll[5][64];
  // LDS = 17408+2304+4608+5120+1280 = 30,720 B -> 3+ blocks/CU; VGPR cap 170 (no spill)

  int tid = threadIdx.x;
  int p0 = blockIdx.x * 64;

  for (int i = tid; i < 9 * 64; i += 256)   WpS[0][i]  = bfbits2f(a.Wp[i]);
  for (int i = tid; i < 18 * 64; i += 256)  WaS[0][i]  = bfbits2f(a.Wa[i]);
  if (tid < 64) {
    #pragma unroll
    for (int s = 0; s < 5; s++) pvAll[s][tid] = a.pv[s][p0 + tid];
  }
  float4 pt = make_float4(0.f, 0.f, 0.f, 0.f);
  if (tid < 64) {
    ushort4 pu = a.points[p0 + tid];
    pt = make_float4(bfbits2f(pu.x), bfbits2f(pu.y), bfbits2f(pu.z), bfbits2f(pu.w));
  }
  __syncthreads();

  int pr = tid & 7;        // point row 0..7 (points pr, pr+8, ..., pr+56)
  int cg = tid >> 3;       // 0..31
  int cb4 = cg << 2;       // channel base (4 channels)

  float acc[8][4];
  #pragma unroll
  for (int j = 0; j < 8; j++)
    #pragma unroll
    for (int l = 0; l < 4; l++) acc[j][l] = 0.0f;

  const uint2* Bg = (const uint2*)a.Wpo;   // uint2 = 4 bf16 = channels [cb4..cb4+3] at word cg

  #pragma unroll 1
  for (int kc = 0; kc < 6; kc++) {
    int s = kc >> 1;
    if ((kc & 1) == 0) {
      // recompute final_s for the 64 points
      if (tid < 64) {
        int v = pvAll[s][tid];
        const float* st = a.stats[s] + (size_t)v * 10;
        float a2k[9];
        #pragma unroll
        for (int k = 0; k < 9; k++) a2k[k] = st[k];
        float vl0 = bfbits2f(a.vlc[s][3 * (p0 + tid) + 0]);
        float vl1 = bfbits2f(a.vlc[s][3 * (p0 + tid) + 1]);
        float* row = attS[tid];
        row[0] = pt.x; row[1] = pt.y; row[2] = pt.z; row[3] = pt.w;
        row[4] = pt.x - a2k[0]; row[5] = pt.y - a2k[1]; row[6] = pt.z - a2k[2];
        row[7] = vl0; row[8] = vl1;
        #pragma unroll
        for (int k = 0; k < 9; k++) row[9 + k] = a2k[k];
      }
      __syncthreads();
      int p = tid >> 2, ch0 = (tid & 3) << 4;
      float pv_[18];
      #pragma unroll
      for (int k = 0; k < 18; k++) pv_[k] = attS[p][k];
      float accp[16], acca[16];
      #pragma unroll
      for (int l = 0; l < 16; l++) { accp[l] = 0.0f; acca[l] = 0.0f; }
      #pragma unroll
      for (int k = 0; k < 9; k++) {
        float x = pv_[k];
        #pragma unroll
        for (int l = 0; l < 16; l++) accp[l] = fmaf(x, WpS[k][ch0 + l], accp[l]);
      }
      #pragma unroll
      for (int k = 0; k < 18; k++) {
        int src = (k < 3) ? (4 + k) : (k == 3) ? 3 : k;
        float x = pv_[src];
        #pragma unroll
        for (int l = 0; l < 16; l++) acca[l] = fmaf(x, WaS[k][ch0 + l], acca[l]);
      }
      #pragma unroll
      for (int l4 = 0; l4 < 16; l4 += 4) {
        float4 f;
        f.x = accp[l4 + 0] * acca[l4 + 0];
        f.y = accp[l4 + 1] * acca[l4 + 1];
        f.z = accp[l4 + 2] * acca[l4 + 2];
        f.w = accp[l4 + 3] * acca[l4 + 3];
        *(float4*)&A[p][ch0 + l4] = f;
      }
    } else {
      // gather vf_s[pv] (decode ordering)
      const unsigned* vfw = a.vf16[s];
      for (int i = tid; i < 2048; i += 256) {
        int p = i >> 5; int wd = i & 31;
        int v = pvAll[s][p];
        unsigned q = vfw[(size_t)v * 32 + wd];
        A[p][2 * wd]     = bfbits2f(dec16(q & 0xFFFFu));
        A[p][2 * wd + 1] = bfbits2f(dec16(q >> 16));
      }
    }
    __syncthreads();
    // GEMM: B read directly from global (L2-resident, one 64B line/wave/load)
    #pragma unroll 2
    for (int kk = 0; kk < 64; kk += 4) {
      uint2 bw[4];
      #pragma unroll
      for (int t = 0; t < 4; t++) bw[t] = Bg[(size_t)(kc * 64 + kk + t) * 32 + cg];
      float4 av[8];
      #pragma unroll
      for (int j = 0; j < 8; j++) av[j] = *(const float4*)&A[pr + (j << 3)][kk];
      #pragma unroll
      for (int t = 0; t < 4; t++) {
        float b0 = __uint_as_float(bw[t].x << 16);
        float b1 = __uint_as_float(bw[t].x & 0xFFFF0000u);
        float b2 = __uint_as_float(bw[t].y << 16);
        float b3 = __uint_as_float(bw[t].y & 0xFFFF0000u);
        #pragma unroll
        for (int j = 0; j < 8; j++) {
          float x = (t == 0) ? av[j].x : (t == 1) ? av[j].y : (t == 2) ? av[j].z : av[j].w;
          acc[j][0] = fmaf(x, b0, acc[j][0]);
          acc[j][1] = fmaf(x, b1, acc[j][1]);
          acc[j][2] = fmaf(x, b2, acc[j][2]);
          acc[j][3] = fmaf(x, b3, acc[j][3]);
        }
      }
    }
    __syncthreads();
  }

  // stage Wao (fp32) into A's LDS space -- A tile is dead after the K loop
  float* WaoE = &A[0][0];
  for (int i = tid; i < 18 * 128; i += 256) WaoE[i] = bfbits2f(a.Wao[i]);

  // epilogue: scales 3 & 4 -> 64-bit CAS-max into G ([v][c] layout)
  #pragma unroll 1
  for (int si = 0; si < 2; si++) {
    if (tid < 64) {
      int v = pvAll[3 + si][tid];
      const float* st = a.stats[3 + si] + (size_t)v * 10;
      float a2k[9];
      #pragma unroll
      for (int k = 0; k < 9; k++) a2k[k] = st[k];
      float vl0 = bfbits2f(a.vlc[3 + si][3 * (p0 + tid) + 0]);
      float vl1 = bfbits2f(a.vlc[3 + si][3 * (p0 + tid) + 1]);
      float plc0 = pt.x - a2k[0], plc1 = pt.y - a2k[1], plc2 = pt.z - a2k[2];
      float* row = attS[tid];
      row[0] = plc0; row[1] = plc1; row[2] = plc2; row[3] = pt.w;
      row[4] = plc0; row[5] = plc1; row[6] = plc2; row[7] = vl0; row[8] = vl1;
      #pragma unroll
      for (int k = 0; k < 9; k++) row[9 + k] = a2k[k];
    }
    __syncthreads();   // covers WaoE staging (si=0) and attS rebuild (both)
    size_t gbase = si ? (size_t)G4_OFF : 0;
    float afc[8][4];
    #pragma unroll
    for (int j = 0; j < 8; j++)
      #pragma unroll
      for (int l = 0; l < 4; l++) afc[j][l] = 0.0f;
    #pragma unroll
    for (int k = 0; k < 18; k++) {
      float4 w = *(const float4*)&WaoE[k * 128 + cb4];
      #pragma unroll
      for (int j = 0; j < 8; j++) {
        float x = attS[pr + (j << 3)][k];
        afc[j][0] = fmaf(x, w.x, afc[j][0]);
        afc[j][1] = fmaf(x, w.y, afc[j][1]);
        afc[j][2] = fmaf(x, w.z, afc[j][2]);
        afc[j][3] = fmaf(x, w.w, afc[j][3]);
      }
    }
    #pragma unroll
    for (int j = 0; j < 8; j++) {
      int p = pr + (j << 3);
      int v = pvAll[3 + si][p];
      u64 e = (u64)enc16(f2bf(afc[j][0] * acc[j][0]))
            | ((u64)enc16(f2bf(afc[j][1] * acc[j][1])) << 16)
            | ((u64)enc16(f2bf(afc[j][2] * acc[j][2])) << 32)
            | ((u64)enc16(f2bf(afc[j][3] * acc[j][3])) << 48);
      casMax64((u64*)(a.G + gbase + (size_t)v * 128 + cb4), e);
    }
    __syncthreads();
  }
}

// ---------------- K5: clear all of d_out ----------------
__global__ void k_clear(unsigned* __restrict__ outw) {
  int i = blockIdx.x * blockDim.x + threadIdx.x;
  if (i < OUT_ELEMS / 2) outw[i] = 0u;
}

// ---------------- K6: scatter G -> dense output, LDS-transposed tiles ----------------
__global__ void __launch_bounds__(256) k_scatter_out(const ushort_t* __restrict__ G,
                                                     const int* __restrict__ vfs3,
                                                     const int* __restrict__ vfs4,
                                                     ushort_t* __restrict__ out16) {
  __shared__ ushort_t tile[32][130];   // pad 130 -> conflict-free column reads
  __shared__ int vbase[32];
  int blk = blockIdx.x;
  int s = (blk >= NB3) ? 1 : 0;
  int v0 = (s ? (blk - NB3) : blk) * 32;
  int V = s ? 10000 : 20000;
  int HW = s ? HW4 : HW3;
  int W = s ? 94 : 188;
  const int* vfs = s ? vfs4 : vfs3;
  size_t goff = s ? (size_t)G4_OFF : 0;
  size_t ooff = s ? (size_t)OUT4_OFF : 0;
  int nv = min(32, V - v0);
  int tid = threadIdx.x;
  const unsigned* gw = (const unsigned*)(G + goff);
  for (int i = tid; i < nv * 64; i += 256) {
    int vi = i >> 6, cw = i & 63;
    unsigned q = gw[(size_t)(v0 + vi) * 64 + cw];
    tile[vi][2 * cw]     = (ushort_t)(q & 0xFFFFu);
    tile[vi][2 * cw + 1] = (ushort_t)(q >> 16);
  }
  if (tid < nv) {
    int v = v0 + tid;
    int b = vfs[3 * v], y = vfs[3 * v + 1], x = vfs[3 * v + 2];
    vbase[tid] = (b * 128) * HW + y * W + x;
  }
  __syncthreads();
  for (int i = tid; i < 128 * 32; i += 256) {
    int c = i >> 5, vi = i & 31;
    if (vi < nv) {
      unsigned d = dec16(tile[vi][c]);
      if ((d & 0x7F80u) == 0x7F80u) d = (d & 0x8000u) | 0x7F7Fu;  // scrub
      out16[ooff + (size_t)vbase[vi] + (size_t)c * HW] = (ushort_t)d;
    }
  }
}

// ---------------- host ----------------
extern "C" void kernel_launch(void* const* d_in, const int* in_sizes, int n_in,
                              void* d_out, int out_size, void* d_ws, size_t ws_size,
                              hipStream_t stream) {
  static const int VOX[5] = {40000, 20000, 10000, 20000, 10000};

  const ushort_t* points = (const ushort_t*)d_in[0];
  const ushort_t* vlc[5]; const int* pv[5]; const int* vfs[5];
  const ushort_t *Wp, *Wa, *Wpo, *Wao;
  if (in_sizes[2] == N_PTS) {
    for (int s = 0; s < 5; s++) {
      vlc[s] = (const ushort_t*)d_in[1 + 3 * s];
      pv[s]  = (const int*)     d_in[2 + 3 * s];
      vfs[s] = (const int*)     d_in[3 + 3 * s];
    }
    Wp  = (const ushort_t*)d_in[16];
    Wa  = (const ushort_t*)d_in[17];
    Wpo = (const ushort_t*)d_in[18];
    Wao = (const ushort_t*)d_in[19];
  } else {
    for (int s = 0; s < 5; s++) vlc[s] = (const ushort_t*)d_in[1 + s];
    Wp  = (const ushort_t*)d_in[6];
    Wa  = (const ushort_t*)d_in[7];
    Wpo = (const ushort_t*)d_in[8];
    Wao = (const ushort_t*)d_in[9];
    for (int s = 0; s < 5; s++) pv[s]  = (const int*)d_in[10 + s];
    for (int s = 0; s < 5; s++) vfs[s] = (const int*)d_in[15 + s];
  }

  // scratch: stats + vf16 inside d_out; G (vf3/vf4 enc) in d_ws (7.68 MB)
  float* statsBase = (float*)d_out;
  unsigned* outw = (unsigned*)d_out;
  unsigned* fBase = outw + S_FLOATS;
  ushort_t* G = (ushort_t*)d_ws;
  ushort_t* out16 = (ushort_t*)d_out;

  float* stats[5];
  size_t offS = 0;
  for (int s = 0; s < 5; s++) { stats[s] = statsBase + offS; offS += (size_t)VOX[s] * 10; }
  unsigned* vf16[3];
  size_t offF = 0;
  for (int s = 0; s < 3; s++) { vf16[s] = fBase + offF; offF += (size_t)VOX[s] * 32; }

  ScaleArgs sa;
  for (int s = 0; s < 5; s++) { sa.vlc[s] = vlc[s]; sa.pv[s] = pv[s]; sa.stats[s] = stats[s]; }
  for (int s = 0; s < 3; s++) sa.vf16[s] = vf16[s];

  int totInit = S_FLOATS + F_UINTS + G_USHORTS / 2;
  k_init<<<(totInit + 255) / 256, 256, 0, stream>>>(outw, (unsigned*)d_ws);

  k_segsum<<<(N_PTS + 255) / 256, 256, 0, stream>>>((const ushort4*)points, sa);

  k_voxstats<<<(100000 + 255) / 256, 256, 0, stream>>>(sa);

  k_scale012<<<(N_PTS + 255) / 256, 256, 0, stream>>>((const ushort4*)points, sa, Wp, Wa);

  K4Args ka;
  ka.points = (const ushort4*)points;
  for (int s = 0; s < 5; s++) { ka.vlc[s] = vlc[s]; ka.pv[s] = pv[s]; ka.stats[s] = stats[s]; }
  for (int s = 0; s < 3; s++) ka.vf16[s] = vf16[s];
  ka.G = G;
  ka.Wp = Wp; ka.Wa = Wa; ka.Wpo = Wpo; ka.Wao = Wao;
  k_big<<<N_PTS / 64, 256, 0, stream>>>(ka);

  k_clear<<<(OUT_ELEMS / 2 + 255) / 256, 256, 0, stream>>>(outw);

  k_scatter_out<<<NB3 + NB4, 256, 0, stream>>>(G, vfs[3], vfs[4], out16);
}

// Round 12
// 1361.067 us; speedup vs baseline: 1.7528x; 1.2211x over previous
//
#include <hip/hip_runtime.h>
#include <stdint.h>

#define N_PTS 200000
#define HW3 35344            // 188*188
#define HW4 8836             // 94*94
#define OUT4_OFF 9048064     // 2*128*HW3
#define OUT_ELEMS 11310080   // OUT4_OFF + 2*128*HW4
// d_out scratch layout (ushort indices): stats [0,2M), vf16 [2M,6.48M)
#define S_FLOATS 1000000     // 100000 voxels * 10 fp32
#define F_UINTS  2240000     // 70000 voxels * 32 uint (64ch enc16 pairs)
#define G_USHORTS 3840000    // 30000 voxels * 128 enc16 (in d_ws)
#define G4_OFF 2560000       // vf4enc offset inside G
#define NB3 625              // 20000/32 scatter blocks, scale 3
#define NB4 313              // ceil(10000/32), scale 4
typedef unsigned short ushort_t;
typedef unsigned long long u64;

// ---- bf16 <-> fp32 ----
__device__ __forceinline__ float bfbits2f(unsigned hbits16) {
  return __uint_as_float(hbits16 << 16);
}
// RNE float->bf16 with NaN->0 and inf-saturation (output can never be NaN/inf)
__device__ __forceinline__ ushort_t f2bf(float f) {
  if (!(f == f)) return (ushort_t)0;                      // NaN -> +0
  unsigned u = __float_as_uint(f);
  if ((u & 0x7F800000u) == 0x7F800000u)                   // +-inf -> +-max finite
    return (ushort_t)(((u >> 16) & 0x8000u) | 0x7F7Fu);
  unsigned r = u + 0x7FFFu + ((u >> 16) & 1u);
  ushort_t h = (ushort_t)(r >> 16);
  if ((h & 0x7FFFu) == 0x7F80u) h = (ushort_t)((h & 0x8000u) | 0x7F7Fu); // rounded to inf
  return h;
}
// order-preserving 16-bit encode of bf16 bits
__device__ __forceinline__ unsigned enc16(unsigned h) {
  return (h & 0x8000u) ? (h ^ 0xFFFFu) : (h | 0x8000u);
}
__device__ __forceinline__ unsigned dec16(unsigned e) {
  return (e & 0x8000u) ? (e & 0x7FFFu) : (e ^ 0xFFFFu);
}
// enc16(0xFF7F = saturated FINFO_MIN) == 0x0080 (init value for max-buffers)

// 4x16-bit lane-wise scatter-max via 64-bit CAS (values monotone; masked compare
// works because same bit positions compare identically)
__device__ __forceinline__ void casMax64(u64* w, u64 enc) {
  u64 old = *w;
  while (true) {
    u64 nw = 0;
    #pragma unroll
    for (int i = 0; i < 4; i++) {
      u64 m = 0xFFFFull << (i * 16);
      u64 av = old & m, bv = enc & m;
      nw |= (av > bv) ? av : bv;
    }
    if (nw == old) break;
    u64 prev = atomicCAS(w, old, nw);
    if (prev == old) break;
    old = prev;
  }
}

struct ScaleArgs {
  const ushort_t* vlc[5];
  const int*      pv[5];
  float*          stats[5];   // in d_out scratch; per voxel stride 10
  unsigned*       vf16[3];    // in d_out scratch; [V][32] uints (2 enc16 ch/word)
};

// ---------------- K0: init scratch regions ----------------
__global__ void k_init(unsigned* __restrict__ outw, unsigned* __restrict__ g) {
  int i = blockIdx.x * blockDim.x + threadIdx.x;
  if (i < S_FLOATS) { outw[i] = 0u; return; }                      // stats = 0.0f
  if (i < S_FLOATS + F_UINTS) { outw[i] = 0x00800080u; return; }   // vf16 init
  i -= S_FLOATS + F_UINTS;
  if (i < G_USHORTS / 2) g[i] = 0x00800080u;                       // vf3/vf4 init
}

// ---------------- K1: per-scale segment sums ----------------
__global__ void __launch_bounds__(256) k_segsum(const ushort4* __restrict__ points, ScaleArgs a) {
  int p = blockIdx.x * blockDim.x + threadIdx.x;
  if (p >= N_PTS) return;
  ushort4 pu = points[p];
  float px = bfbits2f(pu.x), py = bfbits2f(pu.y), pz = bfbits2f(pu.z), pw = bfbits2f(pu.w);
  #pragma unroll
  for (int s = 0; s < 5; s++) {
    int v = a.pv[s][p];
    float l0 = bfbits2f(a.vlc[s][3 * p + 0]);
    float l1 = bfbits2f(a.vlc[s][3 * p + 1]);
    float* st = a.stats[s] + (size_t)v * 10;
    atomicAdd(st + 0, px);
    atomicAdd(st + 1, py);
    atomicAdd(st + 2, pz);
    atomicAdd(st + 3, pw);
    atomicAdd(st + 4, l0);
    atomicAdd(st + 5, l1);
    atomicAdd(st + 9, 1.0f);
  }
}

// ---------------- K2: sums -> a2 (per-voxel means) ----------------
__global__ void k_voxstats(ScaleArgs a) {
  int i = blockIdx.x * blockDim.x + threadIdx.x;
  int s, v;
  if      (i <  40000) { s = 0; v = i; }
  else if (i <  60000) { s = 1; v = i - 40000; }
  else if (i <  70000) { s = 2; v = i - 60000; }
  else if (i <  90000) { s = 3; v = i - 70000; }
  else if (i < 100000) { s = 4; v = i - 90000; }
  else return;
  float* st = a.stats[s] + (size_t)v * 10;
  float cnt = st[9];
  float c = fmaxf(cnt, 1.0f);
  float s0 = st[0], s1 = st[1], s2 = st[2], s3 = st[3], s4 = st[4], s5 = st[5];
  float pm0 = s0 / c, pm1 = s1 / c, pm2 = s2 / c, pm3 = s3 / c;
  float mp0 = (s0 - cnt * pm0) / c;
  float mp1 = (s1 - cnt * pm1) / c;
  float mp2 = (s2 - cnt * pm2) / c;
  float mv0 = s4 / c, mv1 = s5 / c;
  st[0] = pm0; st[1] = pm1; st[2] = pm2; st[3] = pm3;
  st[4] = mp0; st[5] = mp1; st[6] = mp2; st[7] = mv0; st[8] = mv1;
}

// ---------------- K3: scales 0-2, final -> 64-bit CAS-max into vf16 ----------------
__global__ void __launch_bounds__(256) k_scale012(
    const ushort4* __restrict__ points, ScaleArgs a,
    const ushort_t* __restrict__ Wp,   // [9][64] bf16
    const ushort_t* __restrict__ Wa) { // [18][64] bf16
  __shared__ float WpS[9 * 64];
  __shared__ float WaS[18 * 64];
  int tid = threadIdx.x;
  for (int i = tid; i < 9 * 64; i += 256)  WpS[i] = bfbits2f(Wp[i]);
  for (int i = tid; i < 18 * 64; i += 256) WaS[i] = bfbits2f(Wa[i]);
  __syncthreads();

  int p = blockIdx.x * blockDim.x + tid;
  if (p >= N_PTS) return;
  ushort4 pu = points[p];
  float px = bfbits2f(pu.x), py = bfbits2f(pu.y), pz = bfbits2f(pu.z), pw = bfbits2f(pu.w);
  #pragma unroll 1
  for (int s = 0; s < 3; s++) {
    int v = a.pv[s][p];
    const float* st = a.stats[s] + (size_t)v * 10;
    float a2[9];
    #pragma unroll
    for (int k = 0; k < 9; k++) a2[k] = st[k];
    float plc0 = px - a2[0], plc1 = py - a2[1], plc2 = pz - a2[2];
    float vl0 = bfbits2f(a.vlc[s][3 * p + 0]);
    float vl1 = bfbits2f(a.vlc[s][3 * p + 1]);
    float pif[9] = {px, py, pz, pw, plc0, plc1, plc2, vl0, vl1};
    float att[18] = {plc0, plc1, plc2, pw, plc0, plc1, plc2, vl0, vl1,
                     a2[0], a2[1], a2[2], a2[3], a2[4], a2[5], a2[6], a2[7], a2[8]};
    unsigned* vfw = a.vf16[s] + (size_t)v * 32;
    #pragma unroll 1
    for (int cb = 0; cb < 64; cb += 16) {
      float accp[16], acca[16];
      #pragma unroll
      for (int l = 0; l < 16; l++) { accp[l] = 0.0f; acca[l] = 0.0f; }
      #pragma unroll
      for (int k = 0; k < 9; k++) {
        float x = pif[k];
        #pragma unroll
        for (int l = 0; l < 16; l++) accp[l] = fmaf(x, WpS[k * 64 + cb + l], accp[l]);
      }
      #pragma unroll
      for (int k = 0; k < 18; k++) {
        float x = att[k];
        #pragma unroll
        for (int l = 0; l < 16; l++) acca[l] = fmaf(x, WaS[k * 64 + cb + l], acca[l]);
      }
      #pragma unroll
      for (int l = 0; l < 16; l += 4) {
        u64 e = (u64)enc16(f2bf(acca[l] * accp[l]))
              | ((u64)enc16(f2bf(acca[l + 1] * accp[l + 1])) << 16)
              | ((u64)enc16(f2bf(acca[l + 2] * accp[l + 2])) << 32)
              | ((u64)enc16(f2bf(acca[l + 3] * accp[l + 3])) << 48);
        casMax64((u64*)(vfw + ((cb + l) >> 1)), e);
      }
    }
  }
}

// ---------------- K4: fused big GEMM (M=64, B direct from L2) + scales 3/4 -> G ----------------
struct K4Args {
  const ushort4* points;
  const ushort_t* vlc[5];
  const int* pv[5];
  const float* stats[5];
  const unsigned* vf16[3];
  ushort_t* G;               // vf3enc at 0, vf4enc at G4_OFF; [v][c] layout
  const ushort_t* Wp;        // [9][64]
  const ushort_t* Wa;        // [18][64]
  const ushort_t* Wpo;       // [384][128]
  const ushort_t* Wao;       // [18][128]
};

__global__ void __launch_bounds__(256, 2) k_big(K4Args a) {
  __shared__ __align__(16) float A[64][68];   // A tile fp32; reused as WaoE in epilogue
  __shared__ __align__(16) float WpS[9][64];
  __shared__ __align__(16) float WaS[18][64];
  __shared__ __align__(16) float attS[64][20];
  __shared__ int pvAll[5][64];
  // LDS = 17408+2304+4608+5120+1280 = 30,720 B; 128 VGPR (no spill) -> 4 blocks/CU possible

  int tid = threadIdx.x;
  int p0 = blockIdx.x * 64;

  for (int i = tid; i < 9 * 64; i += 256)   WpS[0][i]  = bfbits2f(a.Wp[i]);
  for (int i = tid; i < 18 * 64; i += 256)  WaS[0][i]  = bfbits2f(a.Wa[i]);
  if (tid < 64) {
    #pragma unroll
    for (int s = 0; s < 5; s++) pvAll[s][tid] = a.pv[s][p0 + tid];
  }
  float4 pt = make_float4(0.f, 0.f, 0.f, 0.f);
  if (tid < 64) {
    ushort4 pu = a.points[p0 + tid];
    pt = make_float4(bfbits2f(pu.x), bfbits2f(pu.y), bfbits2f(pu.z), bfbits2f(pu.w));
  }
  __syncthreads();

  int pr = tid & 7;        // point row 0..7 (points pr, pr+8, ..., pr+56)
  int cg = tid >> 3;       // 0..31
  int cb4 = cg << 2;       // channel base (4 channels)

  float acc[8][4];
  #pragma unroll
  for (int j = 0; j < 8; j++)
    #pragma unroll
    for (int l = 0; l < 4; l++) acc[j][l] = 0.0f;

  const uint2* Bg = (const uint2*)a.Wpo;   // uint2 = 4 bf16 = channels [cb4..cb4+3] at word cg

  #pragma unroll 1
  for (int kc = 0; kc < 6; kc++) {
    int s = kc >> 1;
    if ((kc & 1) == 0) {
      // recompute final_s for the 64 points
      if (tid < 64) {
        int v = pvAll[s][tid];
        const float* st = a.stats[s] + (size_t)v * 10;
        float a2k[9];
        #pragma unroll
        for (int k = 0; k < 9; k++) a2k[k] = st[k];
        float vl0 = bfbits2f(a.vlc[s][3 * (p0 + tid) + 0]);
        float vl1 = bfbits2f(a.vlc[s][3 * (p0 + tid) + 1]);
        float* row = attS[tid];
        row[0] = pt.x; row[1] = pt.y; row[2] = pt.z; row[3] = pt.w;
        row[4] = pt.x - a2k[0]; row[5] = pt.y - a2k[1]; row[6] = pt.z - a2k[2];
        row[7] = vl0; row[8] = vl1;
        #pragma unroll
        for (int k = 0; k < 9; k++) row[9 + k] = a2k[k];
      }
      __syncthreads();
      int p = tid >> 2, ch0 = (tid & 3) << 4;
      float pv_[18];
      #pragma unroll
      for (int k = 0; k < 18; k++) pv_[k] = attS[p][k];
      float accp[16], acca[16];
      #pragma unroll
      for (int l = 0; l < 16; l++) { accp[l] = 0.0f; acca[l] = 0.0f; }
      #pragma unroll
      for (int k = 0; k < 9; k++) {
        float x = pv_[k];
        #pragma unroll
        for (int l = 0; l < 16; l++) accp[l] = fmaf(x, WpS[k][ch0 + l], accp[l]);
      }
      #pragma unroll
      for (int k = 0; k < 18; k++) {
        int src = (k < 3) ? (4 + k) : (k == 3) ? 3 : k;
        float x = pv_[src];
        #pragma unroll
        for (int l = 0; l < 16; l++) acca[l] = fmaf(x, WaS[k][ch0 + l], acca[l]);
      }
      #pragma unroll
      for (int l4 = 0; l4 < 16; l4 += 4) {
        float4 f;
        f.x = accp[l4 + 0] * acca[l4 + 0];
        f.y = accp[l4 + 1] * acca[l4 + 1];
        f.z = accp[l4 + 2] * acca[l4 + 2];
        f.w = accp[l4 + 3] * acca[l4 + 3];
        *(float4*)&A[p][ch0 + l4] = f;
      }
    } else {
      // gather vf_s[pv] (decode ordering)
      const unsigned* vfw = a.vf16[s];
      for (int i = tid; i < 2048; i += 256) {
        int p = i >> 5; int wd = i & 31;
        int v = pvAll[s][p];
        unsigned q = vfw[(size_t)v * 32 + wd];
        A[p][2 * wd]     = bfbits2f(dec16(q & 0xFFFFu));
        A[p][2 * wd + 1] = bfbits2f(dec16(q >> 16));
      }
    }
    __syncthreads();
    // GEMM: B read directly from global (L2-resident, one 64B line/wave/load)
    #pragma unroll 2
    for (int kk = 0; kk < 64; kk += 4) {
      uint2 bw[4];
      #pragma unroll
      for (int t = 0; t < 4; t++) bw[t] = Bg[(size_t)(kc * 64 + kk + t) * 32 + cg];
      float4 av[8];
      #pragma unroll
      for (int j = 0; j < 8; j++) av[j] = *(const float4*)&A[pr + (j << 3)][kk];
      #pragma unroll
      for (int t = 0; t < 4; t++) {
        float b0 = __uint_as_float(bw[t].x << 16);
        float b1 = __uint_as_float(bw[t].x & 0xFFFF0000u);
        float b2 = __uint_as_float(bw[t].y << 16);
        float b3 = __uint_as_float(bw[t].y & 0xFFFF0000u);
        #pragma unroll
        for (int j = 0; j < 8; j++) {
          float x = (t == 0) ? av[j].x : (t == 1) ? av[j].y : (t == 2) ? av[j].z : av[j].w;
          acc[j][0] = fmaf(x, b0, acc[j][0]);
          acc[j][1] = fmaf(x, b1, acc[j][1]);
          acc[j][2] = fmaf(x, b2, acc[j][2]);
          acc[j][3] = fmaf(x, b3, acc[j][3]);
        }
      }
    }
    __syncthreads();
  }

  // stage Wao (fp32) into A's LDS space -- A tile is dead after the K loop
  float* WaoE = &A[0][0];
  for (int i = tid; i < 18 * 128; i += 256) WaoE[i] = bfbits2f(a.Wao[i]);

  // epilogue: scales 3 & 4 -> 64-bit CAS-max into G ([v][c] layout)
  #pragma unroll 1
  for (int si = 0; si < 2; si++) {
    if (tid < 64) {
      int v = pvAll[3 + si][tid];
      const float* st = a.stats[3 + si] + (size_t)v * 10;
      float a2k[9];
      #pragma unroll
      for (int k = 0; k < 9; k++) a2k[k] = st[k];
      float vl0 = bfbits2f(a.vlc[3 + si][3 * (p0 + tid) + 0]);
      float vl1 = bfbits2f(a.vlc[3 + si][3 * (p0 + tid) + 1]);
      float plc0 = pt.x - a2k[0], plc1 = pt.y - a2k[1], plc2 = pt.z - a2k[2];
      float* row = attS[tid];
      row[0] = plc0; row[1] = plc1; row[2] = plc2; row[3] = pt.w;
      row[4] = plc0; row[5] = plc1; row[6] = plc2; row[7] = vl0; row[8] = vl1;
      #pragma unroll
      for (int k = 0; k < 9; k++) row[9 + k] = a2k[k];
    }
    __syncthreads();   // covers WaoE staging (si=0) and attS rebuild (both)
    size_t gbase = si ? (size_t)G4_OFF : 0;
    float afc[8][4];
    #pragma unroll
    for (int j = 0; j < 8; j++)
      #pragma unroll
      for (int l = 0; l < 4; l++) afc[j][l] = 0.0f;
    #pragma unroll
    for (int k = 0; k < 18; k++) {
      float4 w = *(const float4*)&WaoE[k * 128 + cb4];
      #pragma unroll
      for (int j = 0; j < 8; j++) {
        float x = attS[pr + (j << 3)][k];
        afc[j][0] = fmaf(x, w.x, afc[j][0]);
        afc[j][1] = fmaf(x, w.y, afc[j][1]);
        afc[j][2] = fmaf(x, w.z, afc[j][2]);
        afc[j][3] = fmaf(x, w.w, afc[j][3]);
      }
    }
    #pragma unroll
    for (int j = 0; j < 8; j++) {
      int p = pr + (j << 3);
      int v = pvAll[3 + si][p];
      u64 e = (u64)enc16(f2bf(afc[j][0] * acc[j][0]))
            | ((u64)enc16(f2bf(afc[j][1] * acc[j][1])) << 16)
            | ((u64)enc16(f2bf(afc[j][2] * acc[j][2])) << 32)
            | ((u64)enc16(f2bf(afc[j][3] * acc[j][3])) << 48);
      casMax64((u64*)(a.G + gbase + (size_t)v * 128 + cb4), e);
    }
    __syncthreads();
  }
}

// ---------------- K5: clear all of d_out ----------------
__global__ void k_clear(unsigned* __restrict__ outw) {
  int i = blockIdx.x * blockDim.x + threadIdx.x;
  if (i < OUT_ELEMS / 2) outw[i] = 0u;
}

// ---------------- K6: scatter G -> dense output, LDS-transposed tiles ----------------
__global__ void __launch_bounds__(256) k_scatter_out(const ushort_t* __restrict__ G,
                                                     const int* __restrict__ vfs3,
                                                     const int* __restrict__ vfs4,
                                                     ushort_t* __restrict__ out16) {
  __shared__ ushort_t tile[32][130];   // pad 130 -> conflict-free column reads
  __shared__ int vbase[32];
  int blk = blockIdx.x;
  int s = (blk >= NB3) ? 1 : 0;
  int v0 = (s ? (blk - NB3) : blk) * 32;
  int V = s ? 10000 : 20000;
  int HW = s ? HW4 : HW3;
  int W = s ? 94 : 188;
  const int* vfs = s ? vfs4 : vfs3;
  size_t goff = s ? (size_t)G4_OFF : 0;
  size_t ooff = s ? (size_t)OUT4_OFF : 0;
  int nv = min(32, V - v0);
  int tid = threadIdx.x;
  const unsigned* gw = (const unsigned*)(G + goff);
  for (int i = tid; i < nv * 64; i += 256) {
    int vi = i >> 6, cw = i & 63;
    unsigned q = gw[(size_t)(v0 + vi) * 64 + cw];
    tile[vi][2 * cw]     = (ushort_t)(q & 0xFFFFu);
    tile[vi][2 * cw + 1] = (ushort_t)(q >> 16);
  }
  if (tid < nv) {
    int v = v0 + tid;
    int b = vfs[3 * v], y = vfs[3 * v + 1], x = vfs[3 * v + 2];
    vbase[tid] = (b * 128) * HW + y * W + x;
  }
  __syncthreads();
  for (int i = tid; i < 128 * 32; i += 256) {
    int c = i >> 5, vi = i & 31;
    if (vi < nv) {
      unsigned d = dec16(tile[vi][c]);
      if ((d & 0x7F80u) == 0x7F80u) d = (d & 0x8000u) | 0x7F7Fu;  // scrub
      out16[ooff + (size_t)vbase[vi] + (size_t)c * HW] = (ushort_t)d;
    }
  }
}

// ---------------- host ----------------
extern "C" void kernel_launch(void* const* d_in, const int* in_sizes, int n_in,
                              void* d_out, int out_size, void* d_ws, size_t ws_size,
                              hipStream_t stream) {
  static const int VOX[5] = {40000, 20000, 10000, 20000, 10000};

  const ushort_t* points = (const ushort_t*)d_in[0];
  const ushort_t* vlc[5]; const int* pv[5]; const int* vfs[5];
  const ushort_t *Wp, *Wa, *Wpo, *Wao;
  if (in_sizes[2] == N_PTS) {
    for (int s = 0; s < 5; s++) {
      vlc[s] = (const ushort_t*)d_in[1 + 3 * s];
      pv[s]  = (const int*)     d_in[2 + 3 * s];
      vfs[s] = (const int*)     d_in[3 + 3 * s];
    }
    Wp  = (const ushort_t*)d_in[16];
    Wa  = (const ushort_t*)d_in[17];
    Wpo = (const ushort_t*)d_in[18];
    Wao = (const ushort_t*)d_in[19];
  } else {
    for (int s = 0; s < 5; s++) vlc[s] = (const ushort_t*)d_in[1 + s];
    Wp  = (const ushort_t*)d_in[6];
    Wa  = (const ushort_t*)d_in[7];
    Wpo = (const ushort_t*)d_in[8];
    Wao = (const ushort_t*)d_in[9];
    for (int s = 0; s < 5; s++) pv[s]  = (const int*)d_in[10 + s];
    for (int s = 0; s < 5; s++) vfs[s] = (const int*)d_in[15 + s];
  }

  // scratch: stats + vf16 inside d_out; G (vf3/vf4 enc) in d_ws (7.68 MB)
  float* statsBase = (float*)d_out;
  unsigned* outw = (unsigned*)d_out;
  unsigned* fBase = outw + S_FLOATS;
  ushort_t* G = (ushort_t*)d_ws;
  ushort_t* out16 = (ushort_t*)d_out;

  float* stats[5];
  size_t offS = 0;
  for (int s = 0; s < 5; s++) { stats[s] = statsBase + offS; offS += (size_t)VOX[s] * 10; }
  unsigned* vf16[3];
  size_t offF = 0;
  for (int s = 0; s < 3; s++) { vf16[s] = fBase + offF; offF += (size_t)VOX[s] * 32; }

  ScaleArgs sa;
  for (int s = 0; s < 5; s++) { sa.vlc[s] = vlc[s]; sa.pv[s] = pv[s]; sa.stats[s] = stats[s]; }
  for (int s = 0; s < 3; s++) sa.vf16[s] = vf16[s];

  int totInit = S_FLOATS + F_UINTS + G_USHORTS / 2;
  k_init<<<(totInit + 255) / 256, 256, 0, stream>>>(outw, (unsigned*)d_ws);

  k_segsum<<<(N_PTS + 255) / 256, 256, 0, stream>>>((const ushort4*)points, sa);

  k_voxstats<<<(100000 + 255) / 256, 256, 0, stream>>>(sa);

  k_scale012<<<(N_PTS + 255) / 256, 256, 0, stream>>>((const ushort4*)points, sa, Wp, Wa);

  K4Args ka;
  ka.points = (const ushort4*)points;
  for (int s = 0; s < 5; s++) { ka.vlc[s] = vlc[s]; ka.pv[s] = pv[s]; ka.stats[s] = stats[s]; }
  for (int s = 0; s < 3; s++) ka.vf16[s] = vf16[s];
  ka.G = G;
  ka.Wp = Wp; ka.Wa = Wa; ka.Wpo = Wpo; ka.Wao = Wao;
  k_big<<<N_PTS / 64, 256, 0, stream>>>(ka);

  k_clear<<<(OUT_ELEMS / 2 + 255) / 256, 256, 0, stream>>>(outw);

  k_scatter_out<<<NB3 + NB4, 256, 0, stream>>>(G, vfs[3], vfs[4], out16);
}